// Round 1
// baseline (1315.458 us; speedup 1.0000x reference)
//
#include <hip/hip_runtime.h>

// ---------------- problem constants ----------------
#define DDIM 1024          // model dim (K of gemm1, N of gemm2)
#define FDIM 2752          // ffn dim
#define FP   2816          // F padded to 22*128 (zero-padded weights -> no N/K guards)
#define TTOK 8192          // tokens
#define SH_OFF 17408       // routed list capacity (16384 + 8*128 align pad), 128-aligned
#define NA   25600         // SH_OFF + TTOK total assignment rows (h rows)

typedef unsigned short u16;
typedef short bf16x8 __attribute__((ext_vector_type(8)));
typedef float f32x4 __attribute__((ext_vector_type(4)));

__device__ __forceinline__ u16 f2b(float f) {
  unsigned u = __float_as_uint(f);
  u += 0x7fff + ((u >> 16) & 1);   // round-to-nearest-even
  return (u16)(u >> 16);
}

// async global->LDS, 16B per lane. LDS dest is wave-uniform base + lane*16.
__device__ __forceinline__ void async16(const void* g, void* s) {
  __builtin_amdgcn_global_load_lds((const __attribute__((address_space(1))) void*)g,
                                   (__attribute__((address_space(3))) void*)s, 16, 0, 0);
}

// ctrl layout (ints): [0..7] counts, [8..15] cursors, [16..24] off[9], [25] nrb_routed, [26] nrb_total

// ---------------- router: 1 wave per token ----------------
__global__ void router_kernel(const float* __restrict__ x, const float* __restrict__ rw,
                              const float* __restrict__ rb, int* __restrict__ topk_id,
                              float* __restrict__ topk_w, int* __restrict__ ctrl) {
  const int wv = threadIdx.x >> 6, lane = threadIdx.x & 63;
  const int t = blockIdx.x * 4 + wv;
  const float* xr = x + (size_t)t * DDIM;
  float acc[8];
#pragma unroll
  for (int e = 0; e < 8; e++) acc[e] = 0.f;
  for (int d = lane; d < DDIM; d += 64) {
    float xv = xr[d];
    const float4* w4 = (const float4*)(rw + (size_t)d * 8);
    float4 wa = w4[0], wb = w4[1];
    acc[0] += xv * wa.x; acc[1] += xv * wa.y; acc[2] += xv * wa.z; acc[3] += xv * wa.w;
    acc[4] += xv * wb.x; acc[5] += xv * wb.y; acc[6] += xv * wb.z; acc[7] += xv * wb.w;
  }
#pragma unroll
  for (int e = 0; e < 8; e++)
    for (int o = 32; o > 0; o >>= 1) acc[e] += __shfl_xor(acc[e], o, 64);
  if (lane == 0) {
    float l[8];
#pragma unroll
    for (int e = 0; e < 8; e++) l[e] = acc[e] + rb[e];
    int i1 = 0; float b1 = l[0];
#pragma unroll
    for (int e = 1; e < 8; e++) if (l[e] > b1) { b1 = l[e]; i1 = e; }
    int i2 = -1; float b2 = -3.4e38f;
#pragma unroll
    for (int e = 0; e < 8; e++) if (e != i1 && l[e] > b2) { b2 = l[e]; i2 = e; }
    // renormalized top-2 softmax weights: w1 = sigmoid(l1-l2)
    float w1 = 1.f / (1.f + __expf(b2 - b1));
    topk_id[2 * t] = i1; topk_id[2 * t + 1] = i2;
    topk_w[2 * t] = w1;  topk_w[2 * t + 1] = 1.f - w1;
    atomicAdd(&ctrl[i1], 1); atomicAdd(&ctrl[i2], 1);
  }
}

// ---------------- offsets + row-block map (single thread, ~200 iters) ----------------
__global__ void build_kernel(int* __restrict__ ctrl, int2* __restrict__ bmap) {
  if (threadIdx.x != 0 || blockIdx.x != 0) return;
  int o = 0, nrb = 0;
  for (int e = 0; e < 8; e++) {
    ctrl[16 + e] = o;
    int c = ctrl[e];
    int nb = (c + 127) >> 7;
    for (int i = 0; i < nb; i++) bmap[nrb++] = make_int2(o + i * 128, e);
    o += nb * 128;            // 128-aligned segments; o <= 17400 < SH_OFF
  }
  ctrl[25] = nrb;             // routed blocks (<=135)
  ctrl[16 + 8] = SH_OFF;
  for (int i = 0; i < 64; i++) bmap[nrb++] = make_int2(SH_OFF + i * 128, 8);
  ctrl[26] = nrb;             // total (<=199)
}

// ---------------- scatter token ids/weights into per-expert segments ----------------
__global__ void fill_kernel(const int* __restrict__ topk_id, const float* __restrict__ topk_w,
                            int* __restrict__ ctrl, int* __restrict__ tok, float* __restrict__ tw) {
  int t = blockIdx.x * 256 + threadIdx.x;
  if (t >= TTOK) return;
#pragma unroll
  for (int k = 0; k < 2; k++) {
    int e = topk_id[2 * t + k];
    int pos = atomicAdd(&ctrl[8 + e], 1);
    int idx = ctrl[16 + e] + pos;
    tok[idx] = t; tw[idx] = topk_w[2 * t + k];
  }
  tok[SH_OFF + t] = t; tw[SH_OFF + t] = 1.0f;
}

// ---------------- x fp32 -> bf16 ----------------
__global__ void cvt_x(const float* __restrict__ x, u16* __restrict__ xb) {
  size_t i = ((size_t)blockIdx.x * 256 + threadIdx.x) * 4;
  float4 v = *(const float4*)(x + i);
  ushort4 o;
  o.x = f2b(v.x); o.y = f2b(v.y); o.z = f2b(v.z); o.w = f2b(v.w);
  *(ushort4*)(xb + i) = o;
}

// ---------------- transpose+cast: out[c][r] = in[r][c] (0 outside R/C) ----------------
// out dims [Cp][Rp] row-major. grid (Rp/64, Cp/64, 9); z==8 uses the shared-expert tensor.
__global__ void transpose_cvt(const float* __restrict__ inE, const float* __restrict__ inSh,
                              u16* __restrict__ out, int R, int C, int Cp, int Rp) {
  const float* in = (blockIdx.z < 8) ? inE + (size_t)blockIdx.z * R * C : inSh;
  u16* o = out + (size_t)blockIdx.z * Cp * Rp;
  __shared__ float tile[64 * 65];
  int r0 = blockIdx.x * 64, c0 = blockIdx.y * 64;
#pragma unroll
  for (int i = 0; i < 16; i++) {
    int idx = threadIdx.x + 256 * i;
    int ri = idx >> 6, ci = idx & 63;
    int r = r0 + ri, c = c0 + ci;
    float v = 0.f;
    if (r < R && c < C) v = in[(size_t)r * C + c];
    tile[ci * 65 + ri] = v;
  }
  __syncthreads();
#pragma unroll
  for (int i = 0; i < 16; i++) {
    int idx = threadIdx.x + 256 * i;
    int co = idx >> 6, ro = idx & 63;
    o[(size_t)(c0 + co) * Rp + (r0 + ro)] = f2b(tile[co * 65 + ro]);
  }
}

// ---------------- GEMM1: h = silu(Xg)*(Xu), grouped by expert ----------------
// A: gathered token rows of xb [m][k=d], B: wg/wu [9][FP][D] ([n=f][k=d]). 128x128 tile, BK=32.
__global__ __launch_bounds__(256, 2)
void gemm_gateup(const u16* __restrict__ xb, const u16* __restrict__ wg, const u16* __restrict__ wu,
                 const int* __restrict__ ctrl, const int2* __restrict__ bmap,
                 const int* __restrict__ tok, u16* __restrict__ h) {
  if ((int)blockIdx.x >= ctrl[26]) return;
  int2 be = bmap[blockIdx.x];
  const int row0 = be.x, e = be.y;
  const int n0 = blockIdx.y * 128;

  __shared__ u16 sA[128 * 32];
  __shared__ u16 sBg[128 * 32];
  __shared__ u16 sBu[128 * 32];

  const int tid = threadIdx.x;
  const int ra = tid >> 2, c16 = tid & 3;
  const int ub0 = (tid & 192) * 8;       // wave-uniform LDS base (ushort units), j=0
  const int ub1 = ub0 + 2048;            // j=1 (+256 chunks * 8 ushorts)

  const u16* a0 = xb + (size_t)tok[row0 + ra] * DDIM + c16 * 8;
  const u16* a1 = xb + (size_t)tok[row0 + 64 + ra] * DDIM + c16 * 8;
  const u16* g0 = wg + ((size_t)e * FP + n0 + ra) * DDIM + c16 * 8;
  const u16* g1 = g0 + (size_t)64 * DDIM;
  const u16* u0 = wu + ((size_t)e * FP + n0 + ra) * DDIM + c16 * 8;
  const u16* u1 = u0 + (size_t)64 * DDIM;

  const int lane = tid & 63, wv = tid >> 6;
  const int mb = (wv >> 1) * 64, nb = (wv & 1) * 64;
  const int fr = lane & 15, kq = lane >> 4;

  f32x4 accg[16], accu[16];
#pragma unroll
  for (int i = 0; i < 16; i++) { accg[i] = (f32x4)(0.0f); accu[i] = (f32x4)(0.0f); }

  for (int kk = 0; kk < DDIM; kk += 32) {
    async16(a0 + kk, sA + ub0);
    async16(a1 + kk, sA + ub1);
    async16(g0 + kk, sBg + ub0);
    async16(g1 + kk, sBg + ub1);
    async16(u0 + kk, sBu + ub0);
    async16(u1 + kk, sBu + ub1);
    __syncthreads();
    bf16x8 af[4], bg[4], bu[4];
#pragma unroll
    for (int i = 0; i < 4; i++) {
      af[i] = *(const bf16x8*)(sA + (mb + i * 16 + fr) * 32 + kq * 8);
      bg[i] = *(const bf16x8*)(sBg + (nb + i * 16 + fr) * 32 + kq * 8);
      bu[i] = *(const bf16x8*)(sBu + (nb + i * 16 + fr) * 32 + kq * 8);
    }
#pragma unroll
    for (int mi = 0; mi < 4; mi++)
#pragma unroll
      for (int ni = 0; ni < 4; ni++) {
        accg[mi * 4 + ni] = __builtin_amdgcn_mfma_f32_16x16x32_bf16(af[mi], bg[ni], accg[mi * 4 + ni], 0, 0, 0);
        accu[mi * 4 + ni] = __builtin_amdgcn_mfma_f32_16x16x32_bf16(af[mi], bu[ni], accu[mi * 4 + ni], 0, 0, 0);
      }
    __syncthreads();
  }
  // epilogue: h = silu(g)*u, bf16. C layout: col=lane&15, row=(lane>>4)*4+reg
#pragma unroll
  for (int mi = 0; mi < 4; mi++)
#pragma unroll
    for (int ni = 0; ni < 4; ni++) {
      f32x4 g = accg[mi * 4 + ni], u = accu[mi * 4 + ni];
#pragma unroll
      for (int r = 0; r < 4; r++) {
        float gv = g[r];
        float hv = (gv * u[r]) / (1.0f + __expf(-gv));
        int row = row0 + mb + mi * 16 + kq * 4 + r;
        int col = n0 + nb + ni * 16 + fr;
        h[(size_t)row * FP + col] = f2b(hv);
      }
    }
}

// ---------------- GEMM2: y += w * (h @ down) ----------------
// ATOMIC=0: shared expert blocks, plain stores (covers every output element once).
// ATOMIC=1: routed blocks via bmap, atomicAdd scaled by routing weight.
template <int ATOMIC>
__global__ __launch_bounds__(256, 2)
void gemm_down(const u16* __restrict__ h, const u16* __restrict__ wd,
               const int* __restrict__ ctrl, const int2* __restrict__ bmap,
               const int* __restrict__ tok, const float* __restrict__ tw,
               float* __restrict__ out) {
  int row0, e;
  if (ATOMIC) {
    if ((int)blockIdx.x >= ctrl[25]) return;
    int2 be = bmap[blockIdx.x];
    row0 = be.x; e = be.y;
  } else {
    row0 = SH_OFF + blockIdx.x * 128; e = 8;
  }
  const int n0 = blockIdx.y * 128;

  __shared__ u16 sA[128 * 32];
  __shared__ u16 sB[128 * 32];

  const int tid = threadIdx.x;
  const int ra = tid >> 2, c16 = tid & 3;
  const int ub0 = (tid & 192) * 8, ub1 = ub0 + 2048;

  const u16* a0 = h + (size_t)(row0 + ra) * FP + c16 * 8;
  const u16* a1 = a0 + (size_t)64 * FP;
  const u16* b0 = wd + ((size_t)e * DDIM + n0 + ra) * FP + c16 * 8;
  const u16* b1 = b0 + (size_t)64 * FP;

  const int lane = tid & 63, wv = tid >> 6;
  const int mb = (wv >> 1) * 64, nb = (wv & 1) * 64;
  const int fr = lane & 15, kq = lane >> 4;

  f32x4 acc[16];
#pragma unroll
  for (int i = 0; i < 16; i++) acc[i] = (f32x4)(0.0f);

  for (int kk = 0; kk < FP; kk += 32) {
    async16(a0 + kk, sA + ub0);
    async16(a1 + kk, sA + ub1);
    async16(b0 + kk, sB + ub0);
    async16(b1 + kk, sB + ub1);
    __syncthreads();
    bf16x8 af[4], bf[4];
#pragma unroll
    for (int i = 0; i < 4; i++) {
      af[i] = *(const bf16x8*)(sA + (mb + i * 16 + fr) * 32 + kq * 8);
      bf[i] = *(const bf16x8*)(sB + (nb + i * 16 + fr) * 32 + kq * 8);
    }
#pragma unroll
    for (int mi = 0; mi < 4; mi++)
#pragma unroll
      for (int ni = 0; ni < 4; ni++)
        acc[mi * 4 + ni] = __builtin_amdgcn_mfma_f32_16x16x32_bf16(af[mi], bf[ni], acc[mi * 4 + ni], 0, 0, 0);
    __syncthreads();
  }

#pragma unroll
  for (int mi = 0; mi < 4; mi++)
#pragma unroll
    for (int r = 0; r < 4; r++) {
      int row = row0 + mb + mi * 16 + kq * 4 + r;
      if (ATOMIC) {
        float w = tw[row];
        if (w != 0.0f) {
          int t = tok[row];
          float* orow = out + (size_t)t * DDIM;
#pragma unroll
          for (int ni = 0; ni < 4; ni++) {
            int col = n0 + nb + ni * 16 + fr;
            atomicAdd(&orow[col], w * acc[mi * 4 + ni][r]);
          }
        }
      } else {
        int t = row - SH_OFF;
        float* orow = out + (size_t)t * DDIM;
#pragma unroll
        for (int ni = 0; ni < 4; ni++) {
          int col = n0 + nb + ni * 16 + fr;
          orow[col] = acc[mi * 4 + ni][r];
        }
      }
    }
}

// ---------------- host ----------------
extern "C" void kernel_launch(void* const* d_in, const int* in_sizes, int n_in,
                              void* d_out, int out_size, void* d_ws, size_t ws_size,
                              hipStream_t stream) {
  const float* x       = (const float*)d_in[0];
  const float* rw      = (const float*)d_in[1];
  const float* rb      = (const float*)d_in[2];
  const float* gate_w  = (const float*)d_in[3];
  const float* up_w    = (const float*)d_in[4];
  const float* down_w  = (const float*)d_in[5];
  const float* sh_gate = (const float*)d_in[6];
  const float* sh_up   = (const float*)d_in[7];
  const float* sh_down = (const float*)d_in[8];
  float* out = (float*)d_out;
  char* ws = (char*)d_ws;

  // ws layout (bytes)
  const size_t O_CTRL = 0;                       // 64 ints
  const size_t O_BMAP = 256;                     // int2[256]
  const size_t O_TID  = 2304;                    // int[T*2]
  const size_t O_TW   = O_TID + (size_t)TTOK * 2 * 4;
  const size_t O_TOK  = O_TW + (size_t)TTOK * 2 * 4;
  const size_t O_TKW  = O_TOK + (size_t)NA * 4;
  const size_t O_ZEND = O_TKW + (size_t)NA * 4;  // everything above zeroed
  const size_t O_XB   = (O_ZEND + 255) & ~(size_t)255;
  const size_t O_WG   = O_XB + (size_t)TTOK * DDIM * 2;
  const size_t O_WU   = O_WG + (size_t)9 * FP * DDIM * 2;
  const size_t O_WD   = O_WU + (size_t)9 * FP * DDIM * 2;
  const size_t O_H    = O_WD + (size_t)9 * DDIM * FP * 2;

  int*   ctrl = (int*)(ws + O_CTRL);
  int2*  bmap = (int2*)(ws + O_BMAP);
  int*   tid_ = (int*)(ws + O_TID);
  float* tw_  = (float*)(ws + O_TW);
  int*   tok  = (int*)(ws + O_TOK);
  float* tkw  = (float*)(ws + O_TKW);
  u16*   xb   = (u16*)(ws + O_XB);
  u16*   wg   = (u16*)(ws + O_WG);
  u16*   wu   = (u16*)(ws + O_WU);
  u16*   wd   = (u16*)(ws + O_WD);
  u16*   h    = (u16*)(ws + O_H);

  hipMemsetAsync(ws, 0, O_ZEND, stream);

  cvt_x<<<dim3(TTOK * DDIM / 1024), 256, 0, stream>>>(x, xb);
  // gate/up: in [D][F] -> out [FP][D]
  transpose_cvt<<<dim3(16, 44, 9), 256, 0, stream>>>(gate_w, sh_gate, wg, DDIM, FDIM, FP, DDIM);
  transpose_cvt<<<dim3(16, 44, 9), 256, 0, stream>>>(up_w, sh_up, wu, DDIM, FDIM, FP, DDIM);
  // down: in [F][D] -> out [D][FP]
  transpose_cvt<<<dim3(44, 16, 9), 256, 0, stream>>>(down_w, sh_down, wd, FDIM, DDIM, DDIM, FP);

  router_kernel<<<dim3(TTOK / 4), 256, 0, stream>>>(x, rw, rb, tid_, tw_, ctrl);
  build_kernel<<<dim3(1), 64, 0, stream>>>(ctrl, bmap);
  fill_kernel<<<dim3(TTOK / 256), 256, 0, stream>>>(tid_, tw_, ctrl, tok, tkw);

  gemm_gateup<<<dim3(200, FP / 128), 256, 0, stream>>>(xb, wg, wu, ctrl, bmap, tok, h);
  gemm_down<0><<<dim3(64, DDIM / 128), 256, 0, stream>>>(h, wd, ctrl, bmap, tok, tkw, out);
  gemm_down<1><<<dim3(136, DDIM / 128), 256, 0, stream>>>(h, wd, ctrl, bmap, tok, tkw, out);
}